// Round 1
// baseline (618.804 us; speedup 1.0000x reference)
//
#include <hip/hip_runtime.h>
#include <math.h>

#define N_NODES 10000
#define N_EDGES 160000
#define N_FEAT  512
#define HEADS   8
#define HID     128

// ---------------------------------------------------------------------------
// GEMM: H[m,o] = sum_k X[m,k] * W[o,k]   (X: [M,K] row-major, W: [O,K] row-major)
// 64x64 tile per 256-thread block, 4x4 per thread, K-tiles of 32.
// ---------------------------------------------------------------------------
#define TM 64
#define TN 64
#define TKK 32

__global__ __launch_bounds__(256)
void gemm_nt(const float* __restrict__ X, const float* __restrict__ W,
             float* __restrict__ H, int M, int K, int O) {
  __shared__ float Xs[TKK][TM + 4];
  __shared__ float Ws[TKK][TN + 4];
  int tid = threadIdx.x;
  int m0 = blockIdx.y * TM;
  int n0 = blockIdx.x * TN;
  int tx = tid & 15;   // col group
  int ty = tid >> 4;   // row group
  float c[4][4] = {};
  for (int k0 = 0; k0 < K; k0 += TKK) {
    #pragma unroll
    for (int it = 0; it < 2; ++it) {
      int idx = tid + it * 256;
      int row = idx >> 3;
      int kq  = idx & 7;
      float4 v = make_float4(0.f, 0.f, 0.f, 0.f);
      if (m0 + row < M)
        v = *(const float4*)&X[(size_t)(m0 + row) * K + k0 + kq * 4];
      Xs[kq*4+0][row] = v.x; Xs[kq*4+1][row] = v.y;
      Xs[kq*4+2][row] = v.z; Xs[kq*4+3][row] = v.w;
      float4 w = *(const float4*)&W[(size_t)(n0 + row) * K + k0 + kq * 4];
      Ws[kq*4+0][row] = w.x; Ws[kq*4+1][row] = w.y;
      Ws[kq*4+2][row] = w.z; Ws[kq*4+3][row] = w.w;
    }
    __syncthreads();
    #pragma unroll
    for (int kk = 0; kk < TKK; ++kk) {
      float4 a = *(const float4*)&Xs[kk][ty * 4];
      float4 b = *(const float4*)&Ws[kk][tx * 4];
      float av[4] = {a.x, a.y, a.z, a.w};
      float bv[4] = {b.x, b.y, b.z, b.w};
      #pragma unroll
      for (int i = 0; i < 4; ++i)
        #pragma unroll
        for (int j = 0; j < 4; ++j)
          c[i][j] = fmaf(av[i], bv[j], c[i][j]);
    }
    __syncthreads();
  }
  #pragma unroll
  for (int i = 0; i < 4; ++i) {
    int row = m0 + ty * 4 + i;
    if (row < M)
      *(float4*)&H[(size_t)row * O + n0 + tx * 4] =
          make_float4(c[i][0], c[i][1], c[i][2], c[i][3]);
  }
}

// ---------------------------------------------------------------------------
// CSR build: histogram of dst, exclusive scan, scatter src by dst bucket
// ---------------------------------------------------------------------------
__global__ void count_kernel(const int* __restrict__ dst, int* __restrict__ deg, int E) {
  int e = blockIdx.x * blockDim.x + threadIdx.x;
  if (e < E) atomicAdd(&deg[dst[e]], 1);
}

__global__ __launch_bounds__(1024)
void scan_kernel(const int* __restrict__ deg, int* __restrict__ off, int N) {
  __shared__ int sums[1024];
  const int PER = 10;  // 1024*10 >= 10000
  int tid = threadIdx.x;
  int base = tid * PER;
  int loc[PER];
  int run = 0;
  #pragma unroll
  for (int j = 0; j < PER; ++j) {
    int v = (base + j < N) ? deg[base + j] : 0;
    run += v;
    loc[j] = run;
  }
  sums[tid] = run;
  __syncthreads();
  // Hillis-Steele inclusive scan over 1024 partials
  for (int o = 1; o < 1024; o <<= 1) {
    int v = (tid >= o) ? sums[tid - o] : 0;
    __syncthreads();
    sums[tid] += v;
    __syncthreads();
  }
  int ex = sums[tid] - run;  // exclusive prefix of this thread's chunk
  if (tid == 0) off[0] = 0;
  #pragma unroll
  for (int j = 0; j < PER; ++j)
    if (base + j < N) off[base + j + 1] = ex + loc[j];
}

__global__ void fill_kernel(const int* __restrict__ src, const int* __restrict__ dst,
                            const int* __restrict__ off, int* __restrict__ cursor,
                            int* __restrict__ ssrc, int E) {
  int e = blockIdx.x * blockDim.x + threadIdx.x;
  if (e < E) {
    int d = dst[e];
    int p = atomicAdd(&cursor[d], 1);
    ssrc[off[d] + p] = src[e];
  }
}

// ---------------------------------------------------------------------------
// Attention scores: si[n,h] = h[n,h,:].a[h,:HID], sj[n,h] = h[n,h,:].a[h,HID:]
// one wave per (n,h)
// ---------------------------------------------------------------------------
__global__ __launch_bounds__(256)
void scores_kernel(const float* __restrict__ h, const float* __restrict__ a,
                   float* __restrict__ si, float* __restrict__ sj, int NH) {
  int w = (blockIdx.x * blockDim.x + threadIdx.x) >> 6;
  int lane = threadIdx.x & 63;
  if (w >= NH) return;
  int head = w & (HEADS - 1);
  const float* hp = h + (size_t)w * HID;
  const float* ap = a + (size_t)head * (2 * HID);
  float v0 = hp[lane], v1 = hp[lane + 64];
  float psi = v0 * ap[lane] + v1 * ap[lane + 64];
  float psj = v0 * ap[HID + lane] + v1 * ap[HID + lane + 64];
  #pragma unroll
  for (int o = 32; o > 0; o >>= 1) {
    psi += __shfl_down(psi, o);
    psj += __shfl_down(psj, o);
  }
  if (lane == 0) { si[w] = psi; sj[w] = psj; }
}

// ---------------------------------------------------------------------------
// Per-dst softmax + weighted aggregation + head-mean + ELU.
// One block per dst node; wave w handles head w; lane l handles dims l, l+64.
// agg = (sum_k exp(e_k - m) * h[src_k]) / (sum_k exp(e_k - m))
// ---------------------------------------------------------------------------
__global__ __launch_bounds__(512)
void gat_aggregate(const float* __restrict__ h, const float* __restrict__ si,
                   const float* __restrict__ sj, const int* __restrict__ off,
                   const int* __restrict__ ssrc, float* __restrict__ emb, int N) {
  int n = blockIdx.x;
  int wave = threadIdx.x >> 6;  // head
  int lane = threadIdx.x & 63;
  int begin = off[n], end = off[n + 1];
  float s_i = si[n * HEADS + wave];

  // pass 1: max score
  float m = -INFINITY;
  for (int k = begin; k < end; ++k) {
    int s = ssrc[k];
    float e = s_i + sj[s * HEADS + wave];
    e = e > 0.f ? e : 0.01f * e;
    m = fmaxf(m, e);
  }
  // pass 2: exp-weights + accumulate
  float denom = 0.f, acc0 = 0.f, acc1 = 0.f;
  for (int k = begin; k < end; ++k) {
    int s = ssrc[k];
    float e = s_i + sj[s * HEADS + wave];
    e = e > 0.f ? e : 0.01f * e;
    float wgt = expf(e - m);
    denom += wgt;
    const float* hp = h + ((size_t)s * HEADS + wave) * HID;
    acc0 += wgt * hp[lane];
    acc1 += wgt * hp[lane + 64];
  }
  float inv = denom > 0.f ? 1.0f / denom : 0.f;
  acc0 *= inv; acc1 *= inv;

  __shared__ float red[HEADS][HID];
  red[wave][lane] = acc0;
  red[wave][lane + 64] = acc1;
  __syncthreads();
  if (threadIdx.x < HID) {
    float s = 0.f;
    #pragma unroll
    for (int hh = 0; hh < HEADS; ++hh) s += red[hh][threadIdx.x];
    s *= (1.0f / HEADS);
    float o = s > 0.f ? s : (expf(s) - 1.0f);  // ELU
    emb[(size_t)n * HID + threadIdx.x] = o;
  }
}

// ---------------------------------------------------------------------------
// Graph pooling: g[d] = sum_n emb2[n,d]  (divide by N later in MLP kernel)
// ---------------------------------------------------------------------------
__global__ __launch_bounds__(256)
void pool_kernel(const float* __restrict__ emb, float* __restrict__ g, int N) {
  __shared__ float part[256];
  int d = threadIdx.x & 127;
  int half = threadIdx.x >> 7;
  int n0 = blockIdx.x * 100;
  float s = 0.f;
  for (int i = half; i < 100; i += 2) {
    int n = n0 + i;
    if (n < N) s += emb[(size_t)n * HID + d];
  }
  part[threadIdx.x] = s;
  __syncthreads();
  if (threadIdx.x < HID) atomicAdd(&g[d], part[threadIdx.x] + part[128 + threadIdx.x]);
}

// ---------------------------------------------------------------------------
// LayerNorm + 3-layer MLP head, single block of 128 threads
// ---------------------------------------------------------------------------
__global__ __launch_bounds__(128)
void mlp_kernel(const float* __restrict__ g, const float* __restrict__ ln_g,
                const float* __restrict__ ln_b, const float* __restrict__ Wl1,
                const float* __restrict__ bl1, const float* __restrict__ Wl2,
                const float* __restrict__ bl2, const float* __restrict__ Wl3,
                const float* __restrict__ bl3, float* __restrict__ out, float invN) {
  __shared__ float red[128];
  __shared__ float gn[128];
  __shared__ float x1[64];
  __shared__ float x2[16];
  int t = threadIdx.x;
  float gg = g[t] * invN;
  red[t] = gg;
  __syncthreads();
  for (int o = 64; o > 0; o >>= 1) {
    if (t < o) red[t] += red[t + o];
    __syncthreads();
  }
  float mu = red[0] * (1.0f / HID);
  __syncthreads();
  float dv = gg - mu;
  red[t] = dv * dv;
  __syncthreads();
  for (int o = 64; o > 0; o >>= 1) {
    if (t < o) red[t] += red[t + o];
    __syncthreads();
  }
  float var = red[0] * (1.0f / HID);
  gn[t] = dv / sqrtf(var + 1e-5f) * ln_g[t] + ln_b[t];
  __syncthreads();
  if (t < 64) {
    float s = bl1[t];
    for (int k = 0; k < 128; ++k) s += Wl1[t * 128 + k] * gn[k];
    x1[t] = s > 0.f ? s : 0.01f * s;
  }
  __syncthreads();
  if (t < 16) {
    float s = bl2[t];
    for (int k = 0; k < 64; ++k) s += Wl2[t * 64 + k] * x1[k];
    x2[t] = s > 0.f ? s : 0.01f * s;
  }
  __syncthreads();
  if (t < 16) {
    float s = bl3[t];
    for (int k = 0; k < 16; ++k) s += Wl3[t * 16 + k] * x2[k];
    out[t] = s > 0.f ? s : 0.f;
  }
}

// ---------------------------------------------------------------------------
extern "C" void kernel_launch(void* const* d_in, const int* in_sizes, int n_in,
                              void* d_out, int out_size, void* d_ws, size_t ws_size,
                              hipStream_t stream) {
  const float* x    = (const float*)d_in[0];
  const int*   esrc = (const int*)d_in[1];
  const int*   edst = (const int*)d_in[2];
  const float* W1   = (const float*)d_in[3];
  const float* a1   = (const float*)d_in[4];
  const float* W2   = (const float*)d_in[5];
  const float* a2   = (const float*)d_in[6];
  const float* ln_g = (const float*)d_in[7];
  const float* ln_b = (const float*)d_in[8];
  const float* Wl1  = (const float*)d_in[9];
  const float* bl1  = (const float*)d_in[10];
  const float* Wl2  = (const float*)d_in[11];
  const float* bl2  = (const float*)d_in[12];
  const float* Wl3  = (const float*)d_in[13];
  const float* bl3  = (const float*)d_in[14];
  float* out = (float*)d_out;

  float* ws   = (float*)d_ws;
  float* h    = ws;                                     // N*8*128 = 10,240,000
  float* si   = h + (size_t)N_NODES * HEADS * HID;      // 80,000
  float* sj   = si + N_NODES * HEADS;                   // 80,000
  float* emb1 = sj + N_NODES * HEADS;                   // 1,280,000
  float* emb2 = emb1 + (size_t)N_NODES * HID;           // 1,280,000
  float* g    = emb2 + (size_t)N_NODES * HID;           // 128
  int*   deg  = (int*)(g + 128);                        // 10,000
  int*   off  = deg + N_NODES;                          // 10,001
  int*   ssrc = off + (N_NODES + 1);                    // 160,000

  // CSR by dst (shared by both layers)
  hipMemsetAsync(deg, 0, N_NODES * sizeof(int), stream);
  count_kernel<<<(N_EDGES + 255) / 256, 256, 0, stream>>>(edst, deg, N_EDGES);
  scan_kernel<<<1, 1024, 0, stream>>>(deg, off, N_NODES);
  hipMemsetAsync(deg, 0, N_NODES * sizeof(int), stream);
  fill_kernel<<<(N_EDGES + 255) / 256, 256, 0, stream>>>(esrc, edst, off, deg, ssrc, N_EDGES);

  dim3 gemm_grid(HEADS * HID / TN, (N_NODES + TM - 1) / TM);

  // Layer 1
  gemm_nt<<<gemm_grid, 256, 0, stream>>>(x, W1, h, N_NODES, N_FEAT, HEADS * HID);
  scores_kernel<<<(N_NODES * HEADS + 3) / 4, 256, 0, stream>>>(h, a1, si, sj, N_NODES * HEADS);
  gat_aggregate<<<N_NODES, 512, 0, stream>>>(h, si, sj, off, ssrc, emb1, N_NODES);

  // Layer 2 (reuse h buffer)
  gemm_nt<<<gemm_grid, 256, 0, stream>>>(emb1, W2, h, N_NODES, HID, HEADS * HID);
  scores_kernel<<<(N_NODES * HEADS + 3) / 4, 256, 0, stream>>>(h, a2, si, sj, N_NODES * HEADS);
  gat_aggregate<<<N_NODES, 512, 0, stream>>>(h, si, sj, off, ssrc, emb2, N_NODES);

  // Pool + MLP head
  hipMemsetAsync(g, 0, HID * sizeof(float), stream);
  pool_kernel<<<100, 256, 0, stream>>>(emb2, g, N_NODES);
  mlp_kernel<<<1, 128, 0, stream>>>(g, ln_g, ln_b, Wl1, bl1, Wl2, bl2, Wl3, bl3,
                                    out, 1.0f / N_NODES);
}

// Round 2
// 525.555 us; speedup vs baseline: 1.1774x; 1.1774x over previous
//
#include <hip/hip_runtime.h>
#include <math.h>

#define N_NODES 10000
#define N_EDGES 160000
#define N_FEAT  512
#define HEADS   8
#define HID     128

typedef __attribute__((ext_vector_type(8))) short bf16x8;
typedef __attribute__((ext_vector_type(4))) float f32x4;

// ---------------------------------------------------------------------------
// fp32 -> (hi, lo) bf16 split.  x ~= bf16(x) + bf16(x - bf16(x)); dropped
// residual <= 2^-18 relative. RNE rounding.
// ---------------------------------------------------------------------------
__device__ inline unsigned short f2bf_rne(float f) {
  unsigned int u = __float_as_uint(f);
  unsigned int r = u + 0x7fffu + ((u >> 16) & 1u);
  return (unsigned short)(r >> 16);
}
__device__ inline float bf2f(unsigned short b) {
  return __uint_as_float(((unsigned int)b) << 16);
}

__global__ __launch_bounds__(256)
void split_kernel(const float* __restrict__ in, unsigned short* __restrict__ hi,
                  unsigned short* __restrict__ lo, int n4) {
  int i = blockIdx.x * blockDim.x + threadIdx.x;
  if (i >= n4) return;
  float4 v = ((const float4*)in)[i];
  ushort4 h, l;
  h.x = f2bf_rne(v.x); l.x = f2bf_rne(v.x - bf2f(h.x));
  h.y = f2bf_rne(v.y); l.y = f2bf_rne(v.y - bf2f(h.y));
  h.z = f2bf_rne(v.z); l.z = f2bf_rne(v.z - bf2f(h.z));
  h.w = f2bf_rne(v.w); l.w = f2bf_rne(v.w - bf2f(h.w));
  ((ushort4*)hi)[i] = h;
  ((ushort4*)lo)[i] = l;
}

// ---------------------------------------------------------------------------
// Split-bf16 MFMA GEMM: C[m,o] = sum_k A[m,k]*B[o,k], A=Ahi+Alo, B=Bhi+Blo
// (3-term MFMA). 128x128 tile / 256 threads; each wave does 64x64 via 4x4
// grid of 16x16x32 MFMAs. LDS row stride 40 bf16 (80B): 16B-aligned b128
// access, 2-way bank aliasing (free).
// ---------------------------------------------------------------------------
#define GM 128
#define GN 128
#define GK 32
#define AST 40

__global__ __launch_bounds__(256)
void gemm_mfma_split(const unsigned short* __restrict__ Ahi,
                     const unsigned short* __restrict__ Alo,
                     const unsigned short* __restrict__ Bhi,
                     const unsigned short* __restrict__ Blo,
                     float* __restrict__ C, int M, int K, int O) {
  __shared__ unsigned short sA[2][GM * AST];
  __shared__ unsigned short sB[2][GN * AST];
  int tid = threadIdx.x;
  int wave = tid >> 6, lane = tid & 63;
  int m0 = blockIdx.y * GM, n0 = blockIdx.x * GN;
  int wm = (wave & 1) * 64, wn = (wave >> 1) * 64;
  int r = lane & 15, q = lane >> 4;

  f32x4 acc[4][4] = {};

  for (int k0 = 0; k0 < K; k0 += GK) {
    // stage 128x32 of A(hi,lo) and B(hi,lo): 2 x 16B per thread per array
    #pragma unroll
    for (int t = 0; t < 2; ++t) {
      int idx = tid + t * 256;        // 0..511
      int row = idx >> 2, kq = idx & 3;
      int arow = m0 + row; if (arow >= M) arow = M - 1;  // clamp (stores masked)
      size_t ga = (size_t)arow * K + k0 + kq * 8;
      int4 vhi = *(const int4*)&Ahi[ga];
      int4 vlo = *(const int4*)&Alo[ga];
      int la = row * AST + kq * 8;
      *(int4*)&sA[0][la] = vhi;
      *(int4*)&sA[1][la] = vlo;
      size_t gb = (size_t)(n0 + row) * K + k0 + kq * 8;  // O % 128 == 0
      int4 whi = *(const int4*)&Bhi[gb];
      int4 wlo = *(const int4*)&Blo[gb];
      *(int4*)&sB[0][la] = whi;
      *(int4*)&sB[1][la] = wlo;
    }
    __syncthreads();
    bf16x8 ah[4], al[4], bh[4], bl[4];
    #pragma unroll
    for (int i = 0; i < 4; ++i) {
      int ra = (wm + i * 16 + r) * AST + q * 8;
      ah[i] = *(const bf16x8*)&sA[0][ra];
      al[i] = *(const bf16x8*)&sA[1][ra];
      int rb = (wn + i * 16 + r) * AST + q * 8;
      bh[i] = *(const bf16x8*)&sB[0][rb];
      bl[i] = *(const bf16x8*)&sB[1][rb];
    }
    #pragma unroll
    for (int i = 0; i < 4; ++i)
      #pragma unroll
      for (int j = 0; j < 4; ++j) {
        acc[i][j] = __builtin_amdgcn_mfma_f32_16x16x32_bf16(ah[i], bh[j], acc[i][j], 0, 0, 0);
        acc[i][j] = __builtin_amdgcn_mfma_f32_16x16x32_bf16(ah[i], bl[j], acc[i][j], 0, 0, 0);
        acc[i][j] = __builtin_amdgcn_mfma_f32_16x16x32_bf16(al[i], bh[j], acc[i][j], 0, 0, 0);
      }
    __syncthreads();
  }
  // C/D layout: col = lane&15, row = (lane>>4)*4 + reg   [m89/m91-verified]
  #pragma unroll
  for (int i = 0; i < 4; ++i) {
    #pragma unroll
    for (int reg = 0; reg < 4; ++reg) {
      int row = m0 + wm + i * 16 + q * 4 + reg;
      if (row < M) {
        #pragma unroll
        for (int j = 0; j < 4; ++j)
          C[(size_t)row * O + n0 + wn + j * 16 + r] = acc[i][j][reg];
      }
    }
  }
}

// ---------------------------------------------------------------------------
// CSR build: histogram of dst, exclusive scan, scatter src by dst bucket
// ---------------------------------------------------------------------------
__global__ void count_kernel(const int* __restrict__ dst, int* __restrict__ deg, int E) {
  int e = blockIdx.x * blockDim.x + threadIdx.x;
  if (e < E) atomicAdd(&deg[dst[e]], 1);
}

__global__ __launch_bounds__(1024)
void scan_kernel(const int* __restrict__ deg, int* __restrict__ off, int N) {
  __shared__ int sums[1024];
  const int PER = 10;
  int tid = threadIdx.x;
  int base = tid * PER;
  int loc[PER];
  int run = 0;
  #pragma unroll
  for (int j = 0; j < PER; ++j) {
    int v = (base + j < N) ? deg[base + j] : 0;
    run += v;
    loc[j] = run;
  }
  sums[tid] = run;
  __syncthreads();
  for (int o = 1; o < 1024; o <<= 1) {
    int v = (tid >= o) ? sums[tid - o] : 0;
    __syncthreads();
    sums[tid] += v;
    __syncthreads();
  }
  int ex = sums[tid] - run;
  if (tid == 0) off[0] = 0;
  #pragma unroll
  for (int j = 0; j < PER; ++j)
    if (base + j < N) off[base + j + 1] = ex + loc[j];
}

__global__ void fill_kernel(const int* __restrict__ src, const int* __restrict__ dst,
                            const int* __restrict__ off, int* __restrict__ cursor,
                            int* __restrict__ ssrc, int E) {
  int e = blockIdx.x * blockDim.x + threadIdx.x;
  if (e < E) {
    int d = dst[e];
    int p = atomicAdd(&cursor[d], 1);
    ssrc[off[d] + p] = src[e];
  }
}

// ---------------------------------------------------------------------------
// Attention scores: si[n,h] = h[n,h,:].a[h,:HID], sj[n,h] = h[n,h,:].a[h,HID:]
// ---------------------------------------------------------------------------
__global__ __launch_bounds__(256)
void scores_kernel(const float* __restrict__ h, const float* __restrict__ a,
                   float* __restrict__ si, float* __restrict__ sj, int NH) {
  int w = (blockIdx.x * blockDim.x + threadIdx.x) >> 6;
  int lane = threadIdx.x & 63;
  if (w >= NH) return;
  int head = w & (HEADS - 1);
  const float* hp = h + (size_t)w * HID;
  const float* ap = a + (size_t)head * (2 * HID);
  float v0 = hp[lane], v1 = hp[lane + 64];
  float psi = v0 * ap[lane] + v1 * ap[lane + 64];
  float psj = v0 * ap[HID + lane] + v1 * ap[HID + lane + 64];
  #pragma unroll
  for (int o = 32; o > 0; o >>= 1) {
    psi += __shfl_down(psi, o);
    psj += __shfl_down(psj, o);
  }
  if (lane == 0) { si[w] = psi; sj[w] = psj; }
}

// ---------------------------------------------------------------------------
// Per-dst softmax + weighted aggregation + head-mean + ELU.
// ---------------------------------------------------------------------------
__global__ __launch_bounds__(512)
void gat_aggregate(const float* __restrict__ h, const float* __restrict__ si,
                   const float* __restrict__ sj, const int* __restrict__ off,
                   const int* __restrict__ ssrc, float* __restrict__ emb, int N) {
  int n = blockIdx.x;
  int wave = threadIdx.x >> 6;  // head
  int lane = threadIdx.x & 63;
  int begin = off[n], end = off[n + 1];
  float s_i = si[n * HEADS + wave];

  float m = -INFINITY;
  for (int k = begin; k < end; ++k) {
    int s = ssrc[k];
    float e = s_i + sj[s * HEADS + wave];
    e = e > 0.f ? e : 0.01f * e;
    m = fmaxf(m, e);
  }
  float denom = 0.f, acc0 = 0.f, acc1 = 0.f;
  for (int k = begin; k < end; ++k) {
    int s = ssrc[k];
    float e = s_i + sj[s * HEADS + wave];
    e = e > 0.f ? e : 0.01f * e;
    float wgt = expf(e - m);
    denom += wgt;
    const float* hp = h + ((size_t)s * HEADS + wave) * HID;
    acc0 += wgt * hp[lane];
    acc1 += wgt * hp[lane + 64];
  }
  float inv = denom > 0.f ? 1.0f / denom : 0.f;
  acc0 *= inv; acc1 *= inv;

  __shared__ float red[HEADS][HID];
  red[wave][lane] = acc0;
  red[wave][lane + 64] = acc1;
  __syncthreads();
  if (threadIdx.x < HID) {
    float s = 0.f;
    #pragma unroll
    for (int hh = 0; hh < HEADS; ++hh) s += red[hh][threadIdx.x];
    s *= (1.0f / HEADS);
    float o = s > 0.f ? s : (expf(s) - 1.0f);  // ELU
    emb[(size_t)n * HID + threadIdx.x] = o;
  }
}

// ---------------------------------------------------------------------------
// Graph pooling: g[d] = sum_n emb2[n,d]
// ---------------------------------------------------------------------------
__global__ __launch_bounds__(256)
void pool_kernel(const float* __restrict__ emb, float* __restrict__ g, int N) {
  __shared__ float part[256];
  int d = threadIdx.x & 127;
  int half = threadIdx.x >> 7;
  int n0 = blockIdx.x * 100;
  float s = 0.f;
  for (int i = half; i < 100; i += 2) {
    int n = n0 + i;
    if (n < N) s += emb[(size_t)n * HID + d];
  }
  part[threadIdx.x] = s;
  __syncthreads();
  if (threadIdx.x < HID) atomicAdd(&g[d], part[threadIdx.x] + part[128 + threadIdx.x]);
}

// ---------------------------------------------------------------------------
// LayerNorm + 3-layer MLP head
// ---------------------------------------------------------------------------
__global__ __launch_bounds__(128)
void mlp_kernel(const float* __restrict__ g, const float* __restrict__ ln_g,
                const float* __restrict__ ln_b, const float* __restrict__ Wl1,
                const float* __restrict__ bl1, const float* __restrict__ Wl2,
                const float* __restrict__ bl2, const float* __restrict__ Wl3,
                const float* __restrict__ bl3, float* __restrict__ out, float invN) {
  __shared__ float red[128];
  __shared__ float gn[128];
  __shared__ float x1[64];
  __shared__ float x2[16];
  int t = threadIdx.x;
  float gg = g[t] * invN;
  red[t] = gg;
  __syncthreads();
  for (int o = 64; o > 0; o >>= 1) {
    if (t < o) red[t] += red[t + o];
    __syncthreads();
  }
  float mu = red[0] * (1.0f / HID);
  __syncthreads();
  float dv = gg - mu;
  red[t] = dv * dv;
  __syncthreads();
  for (int o = 64; o > 0; o >>= 1) {
    if (t < o) red[t] += red[t + o];
    __syncthreads();
  }
  float var = red[0] * (1.0f / HID);
  gn[t] = dv / sqrtf(var + 1e-5f) * ln_g[t] + ln_b[t];
  __syncthreads();
  if (t < 64) {
    float s = bl1[t];
    for (int k = 0; k < 128; ++k) s += Wl1[t * 128 + k] * gn[k];
    x1[t] = s > 0.f ? s : 0.01f * s;
  }
  __syncthreads();
  if (t < 16) {
    float s = bl2[t];
    for (int k = 0; k < 64; ++k) s += Wl2[t * 64 + k] * x1[k];
    x2[t] = s > 0.f ? s : 0.01f * s;
  }
  __syncthreads();
  if (t < 16) {
    float s = bl3[t];
    for (int k = 0; k < 16; ++k) s += Wl3[t * 16 + k] * x2[k];
    out[t] = s > 0.f ? s : 0.f;
  }
}

// ---------------------------------------------------------------------------
extern "C" void kernel_launch(void* const* d_in, const int* in_sizes, int n_in,
                              void* d_out, int out_size, void* d_ws, size_t ws_size,
                              hipStream_t stream) {
  const float* x    = (const float*)d_in[0];
  const int*   esrc = (const int*)d_in[1];
  const int*   edst = (const int*)d_in[2];
  const float* W1   = (const float*)d_in[3];
  const float* a1   = (const float*)d_in[4];
  const float* W2   = (const float*)d_in[5];
  const float* a2   = (const float*)d_in[6];
  const float* ln_g = (const float*)d_in[7];
  const float* ln_b = (const float*)d_in[8];
  const float* Wl1  = (const float*)d_in[9];
  const float* bl1  = (const float*)d_in[10];
  const float* Wl2  = (const float*)d_in[11];
  const float* bl2  = (const float*)d_in[12];
  const float* Wl3  = (const float*)d_in[13];
  const float* bl3  = (const float*)d_in[14];
  float* out = (float*)d_out;

  // workspace carve-up (fp32 elements unless noted)
  float* ws   = (float*)d_ws;
  float* h    = ws;                                     // 10,240,000 f
  float* si   = h + (size_t)N_NODES * HEADS * HID;      // 80,000
  float* sj   = si + N_NODES * HEADS;                   // 80,000
  float* emb1 = sj + N_NODES * HEADS;                   // 1,280,000
  float* emb2 = emb1 + (size_t)N_NODES * HID;           // 1,280,000
  float* g    = emb2 + (size_t)N_NODES * HID;           // 128
  int*   deg  = (int*)(g + 128);                        // 10,000
  int*   off  = deg + N_NODES;                          // 10,001
  int*   ssrc = off + (N_NODES + 1);                    // 160,000
  unsigned short* sAhi = (unsigned short*)(ssrc + N_EDGES + 3);  // 5,120,000 us (X / emb1 split)
  unsigned short* sAlo = sAhi + (size_t)N_NODES * N_FEAT;        // 5,120,000 us
  unsigned short* sBhi = sAlo + (size_t)N_NODES * N_FEAT;        // 524,288 us (W1 / W2 split)
  unsigned short* sBlo = sBhi + HEADS * HID * N_FEAT;            // 524,288 us
  // total ~75 MB

  // CSR by dst (shared by both layers)
  hipMemsetAsync(deg, 0, N_NODES * sizeof(int), stream);
  count_kernel<<<(N_EDGES + 255) / 256, 256, 0, stream>>>(edst, deg, N_EDGES);
  scan_kernel<<<1, 1024, 0, stream>>>(deg, off, N_NODES);
  hipMemsetAsync(deg, 0, N_NODES * sizeof(int), stream);
  fill_kernel<<<(N_EDGES + 255) / 256, 256, 0, stream>>>(esrc, edst, off, deg, ssrc, N_EDGES);

  dim3 gg1(HEADS * HID / GN, (N_NODES + GM - 1) / GM);

  // ---- Layer 1 ----
  {
    int n4 = N_NODES * N_FEAT / 4;
    split_kernel<<<(n4 + 255) / 256, 256, 0, stream>>>(x, sAhi, sAlo, n4);
    int w4 = HEADS * HID * N_FEAT / 4;
    split_kernel<<<(w4 + 255) / 256, 256, 0, stream>>>(W1, sBhi, sBlo, w4);
    gemm_mfma_split<<<gg1, 256, 0, stream>>>(sAhi, sAlo, sBhi, sBlo, h,
                                             N_NODES, N_FEAT, HEADS * HID);
  }
  scores_kernel<<<(N_NODES * HEADS + 3) / 4, 256, 0, stream>>>(h, a1, si, sj, N_NODES * HEADS);
  gat_aggregate<<<N_NODES, 512, 0, stream>>>(h, si, sj, off, ssrc, emb1, N_NODES);

  // ---- Layer 2 (reuse h and split buffers) ----
  {
    int n4 = N_NODES * HID / 4;
    split_kernel<<<(n4 + 255) / 256, 256, 0, stream>>>(emb1, sAhi, sAlo, n4);
    int w4 = HEADS * HID * HID / 4;
    split_kernel<<<(w4 + 255) / 256, 256, 0, stream>>>(W2, sBhi, sBlo, w4);
    gemm_mfma_split<<<gg1, 256, 0, stream>>>(sAhi, sAlo, sBhi, sBlo, h,
                                             N_NODES, HID, HEADS * HID);
  }
  scores_kernel<<<(N_NODES * HEADS + 3) / 4, 256, 0, stream>>>(h, a2, si, sj, N_NODES * HEADS);
  gat_aggregate<<<N_NODES, 512, 0, stream>>>(h, si, sj, off, ssrc, emb2, N_NODES);

  // ---- Pool + MLP head ----
  hipMemsetAsync(g, 0, HID * sizeof(float), stream);
  pool_kernel<<<100, 256, 0, stream>>>(emb2, g, N_NODES);
  mlp_kernel<<<1, 128, 0, stream>>>(g, ln_g, ln_b, Wl1, bl1, Wl2, bl2, Wl3, bl3,
                                    out, 1.0f / N_NODES);
}

// Round 3
// 451.689 us; speedup vs baseline: 1.3700x; 1.1635x over previous
//
#include <hip/hip_runtime.h>
#include <math.h>

#define N_NODES 10000
#define N_EDGES 160000
#define N_FEAT  512
#define HEADS   8
#define HID     128

typedef __attribute__((ext_vector_type(8))) short bf16x8;
typedef __attribute__((ext_vector_type(4))) float f32x4;

// ---------------------------------------------------------------------------
// fp32 -> (hi, lo) bf16 split
// ---------------------------------------------------------------------------
__device__ inline unsigned short f2bf_rne(float f) {
  unsigned int u = __float_as_uint(f);
  unsigned int r = u + 0x7fffu + ((u >> 16) & 1u);
  return (unsigned short)(r >> 16);
}
__device__ inline float bf2f(unsigned short b) {
  return __uint_as_float(((unsigned int)b) << 16);
}

__global__ __launch_bounds__(256)
void split_kernel(const float* __restrict__ in, unsigned short* __restrict__ hi,
                  unsigned short* __restrict__ lo, int n4) {
  int i = blockIdx.x * blockDim.x + threadIdx.x;
  if (i >= n4) return;
  float4 v = ((const float4*)in)[i];
  ushort4 h, l;
  h.x = f2bf_rne(v.x); l.x = f2bf_rne(v.x - bf2f(h.x));
  h.y = f2bf_rne(v.y); l.y = f2bf_rne(v.y - bf2f(h.y));
  h.z = f2bf_rne(v.z); l.z = f2bf_rne(v.z - bf2f(h.z));
  h.w = f2bf_rne(v.w); l.w = f2bf_rne(v.w - bf2f(h.w));
  ((ushort4*)hi)[i] = h;
  ((ushort4*)lo)[i] = l;
}

// ---------------------------------------------------------------------------
// Split-bf16 MFMA GEMM (3-term). 128x128 tile / 256 threads.
// ---------------------------------------------------------------------------
#define GM 128
#define GN 128
#define GK 32
#define AST 40

__global__ __launch_bounds__(256)
void gemm_mfma_split(const unsigned short* __restrict__ Ahi,
                     const unsigned short* __restrict__ Alo,
                     const unsigned short* __restrict__ Bhi,
                     const unsigned short* __restrict__ Blo,
                     float* __restrict__ C, int M, int K, int O) {
  __shared__ unsigned short sA[2][GM * AST];
  __shared__ unsigned short sB[2][GN * AST];
  int tid = threadIdx.x;
  int wave = tid >> 6, lane = tid & 63;
  int m0 = blockIdx.y * GM, n0 = blockIdx.x * GN;
  int wm = (wave & 1) * 64, wn = (wave >> 1) * 64;
  int r = lane & 15, q = lane >> 4;

  f32x4 acc[4][4] = {};

  for (int k0 = 0; k0 < K; k0 += GK) {
    #pragma unroll
    for (int t = 0; t < 2; ++t) {
      int idx = tid + t * 256;
      int row = idx >> 2, kq = idx & 3;
      int arow = m0 + row; if (arow >= M) arow = M - 1;
      size_t ga = (size_t)arow * K + k0 + kq * 8;
      int4 vhi = *(const int4*)&Ahi[ga];
      int4 vlo = *(const int4*)&Alo[ga];
      int la = row * AST + kq * 8;
      *(int4*)&sA[0][la] = vhi;
      *(int4*)&sA[1][la] = vlo;
      size_t gb = (size_t)(n0 + row) * K + k0 + kq * 8;
      int4 whi = *(const int4*)&Bhi[gb];
      int4 wlo = *(const int4*)&Blo[gb];
      *(int4*)&sB[0][la] = whi;
      *(int4*)&sB[1][la] = wlo;
    }
    __syncthreads();
    bf16x8 ah[4], al[4], bh[4], bl[4];
    #pragma unroll
    for (int i = 0; i < 4; ++i) {
      int ra = (wm + i * 16 + r) * AST + q * 8;
      ah[i] = *(const bf16x8*)&sA[0][ra];
      al[i] = *(const bf16x8*)&sA[1][ra];
      int rb = (wn + i * 16 + r) * AST + q * 8;
      bh[i] = *(const bf16x8*)&sB[0][rb];
      bl[i] = *(const bf16x8*)&sB[1][rb];
    }
    #pragma unroll
    for (int i = 0; i < 4; ++i)
      #pragma unroll
      for (int j = 0; j < 4; ++j) {
        acc[i][j] = __builtin_amdgcn_mfma_f32_16x16x32_bf16(ah[i], bh[j], acc[i][j], 0, 0, 0);
        acc[i][j] = __builtin_amdgcn_mfma_f32_16x16x32_bf16(ah[i], bl[j], acc[i][j], 0, 0, 0);
        acc[i][j] = __builtin_amdgcn_mfma_f32_16x16x32_bf16(al[i], bh[j], acc[i][j], 0, 0, 0);
      }
    __syncthreads();
  }
  #pragma unroll
  for (int i = 0; i < 4; ++i) {
    #pragma unroll
    for (int reg = 0; reg < 4; ++reg) {
      int row = m0 + wm + i * 16 + q * 4 + reg;
      if (row < M) {
        #pragma unroll
        for (int j = 0; j < 4; ++j)
          C[(size_t)row * O + n0 + wn + j * 16 + r] = acc[i][j][reg];
      }
    }
  }
}

// ---------------------------------------------------------------------------
// CSR build
// ---------------------------------------------------------------------------
__global__ void count_kernel(const int* __restrict__ dst, int* __restrict__ deg, int E) {
  int e = blockIdx.x * blockDim.x + threadIdx.x;
  if (e < E) atomicAdd(&deg[dst[e]], 1);
}

__global__ __launch_bounds__(1024)
void scan_kernel(const int* __restrict__ deg, int* __restrict__ off, int N) {
  __shared__ int sums[1024];
  const int PER = 10;
  int tid = threadIdx.x;
  int base = tid * PER;
  int loc[PER];
  int run = 0;
  #pragma unroll
  for (int j = 0; j < PER; ++j) {
    int v = (base + j < N) ? deg[base + j] : 0;
    run += v;
    loc[j] = run;
  }
  sums[tid] = run;
  __syncthreads();
  for (int o = 1; o < 1024; o <<= 1) {
    int v = (tid >= o) ? sums[tid - o] : 0;
    __syncthreads();
    sums[tid] += v;
    __syncthreads();
  }
  int ex = sums[tid] - run;
  if (tid == 0) off[0] = 0;
  #pragma unroll
  for (int j = 0; j < PER; ++j)
    if (base + j < N) off[base + j + 1] = ex + loc[j];
}

__global__ void fill_kernel(const int* __restrict__ src, const int* __restrict__ dst,
                            const int* __restrict__ off, int* __restrict__ cursor,
                            int* __restrict__ ssrc, int E) {
  int e = blockIdx.x * blockDim.x + threadIdx.x;
  if (e < E) {
    int d = dst[e];
    int p = atomicAdd(&cursor[d], 1);
    ssrc[off[d] + p] = src[e];
  }
}

// ---------------------------------------------------------------------------
// Attention scores: si/sj per (n,h)
// ---------------------------------------------------------------------------
__global__ __launch_bounds__(256)
void scores_kernel(const float* __restrict__ h, const float* __restrict__ a,
                   float* __restrict__ si, float* __restrict__ sj, int NH) {
  int w = (blockIdx.x * blockDim.x + threadIdx.x) >> 6;
  int lane = threadIdx.x & 63;
  if (w >= NH) return;
  int head = w & (HEADS - 1);
  const float* hp = h + (size_t)w * HID;
  const float* ap = a + (size_t)head * (2 * HID);
  float v0 = hp[lane], v1 = hp[lane + 64];
  float psi = v0 * ap[lane] + v1 * ap[lane + 64];
  float psj = v0 * ap[HID + lane] + v1 * ap[HID + lane + 64];
  #pragma unroll
  for (int o = 32; o > 0; o >>= 1) {
    psi += __shfl_down(psi, o);
    psj += __shfl_down(psj, o);
  }
  if (lane == 0) { si[w] = psi; sj[w] = psj; }
}

// ---------------------------------------------------------------------------
// Edge softmax weights: one wave per dst node. Lane = eidx*8 + head.
// Produces w[k,h] = exp(e - m) (CSR-edge-major) and invden[n,h].
// Segment max/sum across the 8 edge slots via shfl_xor(8,16,32).
// ---------------------------------------------------------------------------
__global__ __launch_bounds__(256)
void alpha_kernel(const float* __restrict__ si, const float* __restrict__ sj,
                  const int* __restrict__ off, const int* __restrict__ ssrc,
                  float* __restrict__ w, float* __restrict__ invden, int N) {
  int wv = (blockIdx.x * blockDim.x + threadIdx.x) >> 6;
  if (wv >= N) return;
  int lane = threadIdx.x & 63;
  int eidx = lane >> 3, head = lane & 7;
  int begin = off[wv], end = off[wv + 1];
  float s_i = si[wv * HEADS + head];

  // pass 1: max
  float m = -INFINITY;
  for (int k0 = begin; k0 < end; k0 += 8) {
    int k = k0 + eidx;
    if (k < end) {
      float e = s_i + sj[ssrc[k] * HEADS + head];
      e = e > 0.f ? e : 0.01f * e;
      m = fmaxf(m, e);
    }
  }
  m = fmaxf(m, __shfl_xor(m, 8));
  m = fmaxf(m, __shfl_xor(m, 16));
  m = fmaxf(m, __shfl_xor(m, 32));

  // pass 2: exp + store + sum
  float sum = 0.f;
  for (int k0 = begin; k0 < end; k0 += 8) {
    int k = k0 + eidx;
    if (k < end) {
      float e = s_i + sj[ssrc[k] * HEADS + head];
      e = e > 0.f ? e : 0.01f * e;
      float wt = expf(e - m);
      w[(size_t)k * HEADS + head] = wt;
      sum += wt;
    }
  }
  sum += __shfl_xor(sum, 8);
  sum += __shfl_xor(sum, 16);
  sum += __shfl_xor(sum, 32);
  if (eidx == 0)
    invden[wv * HEADS + head] = sum > 0.f ? 1.0f / sum : 0.f;
}

// ---------------------------------------------------------------------------
// Aggregation: one block per dst, wave = head, lane covers 2 dims (float2).
// acc = invden * sum_k w[k,h] * h[src_k, h, :]; then head-mean + ELU.
// ---------------------------------------------------------------------------
__global__ __launch_bounds__(512)
void gat_aggregate(const float* __restrict__ h, const float* __restrict__ w,
                   const float* __restrict__ invden, const int* __restrict__ off,
                   const int* __restrict__ ssrc, float* __restrict__ emb, int N) {
  int n = blockIdx.x;
  int wave = threadIdx.x >> 6;  // head
  int lane = threadIdx.x & 63;
  int begin = off[n], end = off[n + 1];

  float ax = 0.f, ay = 0.f;
  int k = begin;
  for (; k + 1 < end; k += 2) {
    int s0 = ssrc[k], s1 = ssrc[k + 1];
    float w0 = w[(size_t)k * HEADS + wave];
    float w1 = w[(size_t)(k + 1) * HEADS + wave];
    const float2* h0 = (const float2*)(h + ((size_t)s0 * HEADS + wave) * HID);
    const float2* h1 = (const float2*)(h + ((size_t)s1 * HEADS + wave) * HID);
    float2 v0 = h0[lane];
    float2 v1 = h1[lane];
    ax = fmaf(w0, v0.x, ax); ay = fmaf(w0, v0.y, ay);
    ax = fmaf(w1, v1.x, ax); ay = fmaf(w1, v1.y, ay);
  }
  if (k < end) {
    int s0 = ssrc[k];
    float w0 = w[(size_t)k * HEADS + wave];
    const float2* h0 = (const float2*)(h + ((size_t)s0 * HEADS + wave) * HID);
    float2 v0 = h0[lane];
    ax = fmaf(w0, v0.x, ax); ay = fmaf(w0, v0.y, ay);
  }
  float inv = invden[n * HEADS + wave];
  ax *= inv; ay *= inv;

  __shared__ float red[HEADS][HID];
  red[wave][lane * 2] = ax;
  red[wave][lane * 2 + 1] = ay;
  __syncthreads();
  if (threadIdx.x < HID) {
    float s = 0.f;
    #pragma unroll
    for (int hh = 0; hh < HEADS; ++hh) s += red[hh][threadIdx.x];
    s *= (1.0f / HEADS);
    float o = s > 0.f ? s : (expf(s) - 1.0f);  // ELU
    emb[(size_t)n * HID + threadIdx.x] = o;
  }
}

// ---------------------------------------------------------------------------
// Graph pooling
// ---------------------------------------------------------------------------
__global__ __launch_bounds__(256)
void pool_kernel(const float* __restrict__ emb, float* __restrict__ g, int N) {
  __shared__ float part[256];
  int d = threadIdx.x & 127;
  int half = threadIdx.x >> 7;
  int n0 = blockIdx.x * 100;
  float s = 0.f;
  for (int i = half; i < 100; i += 2) {
    int n = n0 + i;
    if (n < N) s += emb[(size_t)n * HID + d];
  }
  part[threadIdx.x] = s;
  __syncthreads();
  if (threadIdx.x < HID) atomicAdd(&g[d], part[threadIdx.x] + part[128 + threadIdx.x]);
}

// ---------------------------------------------------------------------------
// LayerNorm + MLP head
// ---------------------------------------------------------------------------
__global__ __launch_bounds__(128)
void mlp_kernel(const float* __restrict__ g, const float* __restrict__ ln_g,
                const float* __restrict__ ln_b, const float* __restrict__ Wl1,
                const float* __restrict__ bl1, const float* __restrict__ Wl2,
                const float* __restrict__ bl2, const float* __restrict__ Wl3,
                const float* __restrict__ bl3, float* __restrict__ out, float invN) {
  __shared__ float red[128];
  __shared__ float gn[128];
  __shared__ float x1[64];
  __shared__ float x2[16];
  int t = threadIdx.x;
  float gg = g[t] * invN;
  red[t] = gg;
  __syncthreads();
  for (int o = 64; o > 0; o >>= 1) {
    if (t < o) red[t] += red[t + o];
    __syncthreads();
  }
  float mu = red[0] * (1.0f / HID);
  __syncthreads();
  float dv = gg - mu;
  red[t] = dv * dv;
  __syncthreads();
  for (int o = 64; o > 0; o >>= 1) {
    if (t < o) red[t] += red[t + o];
    __syncthreads();
  }
  float var = red[0] * (1.0f / HID);
  gn[t] = dv / sqrtf(var + 1e-5f) * ln_g[t] + ln_b[t];
  __syncthreads();
  if (t < 64) {
    float s = bl1[t];
    for (int k = 0; k < 128; ++k) s += Wl1[t * 128 + k] * gn[k];
    x1[t] = s > 0.f ? s : 0.01f * s;
  }
  __syncthreads();
  if (t < 16) {
    float s = bl2[t];
    for (int k = 0; k < 64; ++k) s += Wl2[t * 64 + k] * x1[k];
    x2[t] = s > 0.f ? s : 0.01f * s;
  }
  __syncthreads();
  if (t < 16) {
    float s = bl3[t];
    for (int k = 0; k < 16; ++k) s += Wl3[t * 16 + k] * x2[k];
    out[t] = s > 0.f ? s : 0.f;
  }
}

// ---------------------------------------------------------------------------
extern "C" void kernel_launch(void* const* d_in, const int* in_sizes, int n_in,
                              void* d_out, int out_size, void* d_ws, size_t ws_size,
                              hipStream_t stream) {
  const float* x    = (const float*)d_in[0];
  const int*   esrc = (const int*)d_in[1];
  const int*   edst = (const int*)d_in[2];
  const float* W1   = (const float*)d_in[3];
  const float* a1   = (const float*)d_in[4];
  const float* W2   = (const float*)d_in[5];
  const float* a2   = (const float*)d_in[6];
  const float* ln_g = (const float*)d_in[7];
  const float* ln_b = (const float*)d_in[8];
  const float* Wl1  = (const float*)d_in[9];
  const float* bl1  = (const float*)d_in[10];
  const float* Wl2  = (const float*)d_in[11];
  const float* bl2  = (const float*)d_in[12];
  const float* Wl3  = (const float*)d_in[13];
  const float* bl3  = (const float*)d_in[14];
  float* out = (float*)d_out;

  float* ws   = (float*)d_ws;
  float* h    = ws;                                     // 10,240,000 f
  float* si   = h + (size_t)N_NODES * HEADS * HID;      // 80,000
  float* sj   = si + N_NODES * HEADS;                   // 80,000
  float* emb1 = sj + N_NODES * HEADS;                   // 1,280,000
  float* emb2 = emb1 + (size_t)N_NODES * HID;           // 1,280,000
  float* g    = emb2 + (size_t)N_NODES * HID;           // 128
  float* wbuf = g + 128;                                // E*8 = 1,280,000
  float* invd = wbuf + (size_t)N_EDGES * HEADS;         // 80,000
  int*   deg  = (int*)(invd + N_NODES * HEADS);         // 10,000
  int*   off  = deg + N_NODES;                          // 10,001
  int*   ssrc = off + (N_NODES + 1);                    // 160,000
  unsigned short* sAhi = (unsigned short*)(ssrc + N_EDGES + 3);
  unsigned short* sAlo = sAhi + (size_t)N_NODES * N_FEAT;
  unsigned short* sBhi = sAlo + (size_t)N_NODES * N_FEAT;
  unsigned short* sBlo = sBhi + HEADS * HID * N_FEAT;

  // CSR by dst
  hipMemsetAsync(deg, 0, N_NODES * sizeof(int), stream);
  count_kernel<<<(N_EDGES + 255) / 256, 256, 0, stream>>>(edst, deg, N_EDGES);
  scan_kernel<<<1, 1024, 0, stream>>>(deg, off, N_NODES);
  hipMemsetAsync(deg, 0, N_NODES * sizeof(int), stream);
  fill_kernel<<<(N_EDGES + 255) / 256, 256, 0, stream>>>(esrc, edst, off, deg, ssrc, N_EDGES);

  dim3 gg1(HEADS * HID / GN, (N_NODES + GM - 1) / GM);

  // ---- Layer 1 ----
  {
    int n4 = N_NODES * N_FEAT / 4;
    split_kernel<<<(n4 + 255) / 256, 256, 0, stream>>>(x, sAhi, sAlo, n4);
    int w4 = HEADS * HID * N_FEAT / 4;
    split_kernel<<<(w4 + 255) / 256, 256, 0, stream>>>(W1, sBhi, sBlo, w4);
    gemm_mfma_split<<<gg1, 256, 0, stream>>>(sAhi, sAlo, sBhi, sBlo, h,
                                             N_NODES, N_FEAT, HEADS * HID);
  }
  scores_kernel<<<(N_NODES * HEADS + 3) / 4, 256, 0, stream>>>(h, a1, si, sj, N_NODES * HEADS);
  alpha_kernel<<<(N_NODES + 3) / 4, 256, 0, stream>>>(si, sj, off, ssrc, wbuf, invd, N_NODES);
  gat_aggregate<<<N_NODES, 512, 0, stream>>>(h, wbuf, invd, off, ssrc, emb1, N_NODES);

  // ---- Layer 2 ----
  {
    int n4 = N_NODES * HID / 4;
    split_kernel<<<(n4 + 255) / 256, 256, 0, stream>>>(emb1, sAhi, sAlo, n4);
    int w4 = HEADS * HID * HID / 4;
    split_kernel<<<(w4 + 255) / 256, 256, 0, stream>>>(W2, sBhi, sBlo, w4);
    gemm_mfma_split<<<gg1, 256, 0, stream>>>(sAhi, sAlo, sBhi, sBlo, h,
                                             N_NODES, HID, HEADS * HID);
  }
  scores_kernel<<<(N_NODES * HEADS + 3) / 4, 256, 0, stream>>>(h, a2, si, sj, N_NODES * HEADS);
  alpha_kernel<<<(N_NODES + 3) / 4, 256, 0, stream>>>(si, sj, off, ssrc, wbuf, invd, N_NODES);
  gat_aggregate<<<N_NODES, 512, 0, stream>>>(h, wbuf, invd, off, ssrc, emb2, N_NODES);

  // ---- Pool + MLP head ----
  hipMemsetAsync(g, 0, HID * sizeof(float), stream);
  pool_kernel<<<100, 256, 0, stream>>>(emb2, g, N_NODES);
  mlp_kernel<<<1, 128, 0, stream>>>(g, ln_g, ln_b, Wl1, bl1, Wl2, bl2, Wl3, bl3,
                                    out, 1.0f / N_NODES);
}